// Round 1
// 431.634 us; speedup vs baseline: 1.0453x; 1.0453x over previous
//
#include <hip/hip_runtime.h>

// QLoRA rank-2, FUSED single-pass formulation.
// out[row,d] = 0.5*b_scale[d]*(H0*b_q[d,0] + H1*b_q[d,1]),
//   H_r = a_scale[r] * sum_d x[row,d]*a_q[r,d]
// The computation is row-local, so one block computes h for its 8 rows and
// immediately writes the 8 output rows: 268 MB read + 268 MB write, one
// dispatch, no global h round-trip, read/write streams overlap chip-wide.

#define QL_D    4096
#define QL_ROWS 16384
#define RPB     8   // rows per block

typedef float f32x4 __attribute__((ext_vector_type(4)));

__global__ __launch_bounds__(256) void qlora_fused_kernel(
    const float* __restrict__ x,        // [ROWS, D]
    const int*   __restrict__ a_q,      // [2, D]
    const float* __restrict__ a_scale,  // [2]
    const int*   __restrict__ b_q,      // [D, 2]
    const float* __restrict__ b_scale,  // [D]
    float*       __restrict__ out)      // [ROWS, D]
{
    const int t    = threadIdx.x;
    const int row0 = blockIdx.x * RPB;
    const int wave = t >> 6;
    const int lane = t & 63;

    // ---- Preload A fragment into registers (16 d-entries/thread, both ranks).
    float fa0[16], fa1[16];
    {
        const int4* a0p = (const int4*)a_q;          // rank 0 row
        const int4* a1p = (const int4*)(a_q + QL_D); // rank 1 row
#pragma unroll
        for (int k = 0; k < 4; ++k) {
            const int4 q0 = a0p[t + 256 * k];
            const int4 q1 = a1p[t + 256 * k];
            fa0[4*k+0] = (float)q0.x; fa0[4*k+1] = (float)q0.y;
            fa0[4*k+2] = (float)q0.z; fa0[4*k+3] = (float)q0.w;
            fa1[4*k+0] = (float)q1.x; fa1[4*k+1] = (float)q1.y;
            fa1[4*k+2] = (float)q1.z; fa1[4*k+3] = (float)q1.w;
        }
    }

    __shared__ float sh0[RPB][4], sh1[RPB][4];

    const f32x4* x4 = (const f32x4*)(x + (size_t)row0 * QL_D);
    f32x4*       o4 = (f32x4*)(out + (size_t)row0 * QL_D);

    // ---- Phase 1: rank-2 dot products for RPB rows (streaming, non-temporal).
#pragma unroll
    for (int r = 0; r < RPB; ++r) {
        float h0 = 0.0f, h1 = 0.0f;
#pragma unroll
        for (int k = 0; k < 4; ++k) {
            const f32x4 xv =
                __builtin_nontemporal_load(&x4[r * (QL_D / 4) + t + 256 * k]);
            h0 += xv.x * fa0[4*k+0] + xv.y * fa0[4*k+1]
                + xv.z * fa0[4*k+2] + xv.w * fa0[4*k+3];
            h1 += xv.x * fa1[4*k+0] + xv.y * fa1[4*k+1]
                + xv.z * fa1[4*k+2] + xv.w * fa1[4*k+3];
        }
#pragma unroll
        for (int off = 32; off > 0; off >>= 1) {
            h0 += __shfl_down(h0, off, 64);
            h1 += __shfl_down(h1, off, 64);
        }
        if (lane == 0) { sh0[r][wave] = h0; sh1[r][wave] = h1; }
    }

    // ---- Preload pre-scaled B fragment NOW (latency hides under the barrier;
    //      keeps its 32 VGPRs out of the phase-1 live range).
    float bb0[16], bb1[16];
    {
        const int4*   bq4 = (const int4*)b_q;     // 2 d-entries per int4
        const float4* bs4 = (const float4*)b_scale;
#pragma unroll
        for (int k = 0; k < 4; ++k) {
            const int d4 = t + 256 * k;
            const float4 bs = bs4[d4];
            const int4   q0 = bq4[2 * d4];
            const int4   q1 = bq4[2 * d4 + 1];
            bb0[4*k+0] = 0.5f * bs.x * (float)q0.x; bb1[4*k+0] = 0.5f * bs.x * (float)q0.y;
            bb0[4*k+1] = 0.5f * bs.y * (float)q0.z; bb1[4*k+1] = 0.5f * bs.y * (float)q0.w;
            bb0[4*k+2] = 0.5f * bs.z * (float)q1.x; bb1[4*k+2] = 0.5f * bs.z * (float)q1.y;
            bb0[4*k+3] = 0.5f * bs.w * (float)q1.z; bb1[4*k+3] = 0.5f * bs.w * (float)q1.w;
        }
    }

    __syncthreads();

    // ---- Cross-wave combine + apply a_scale (8 threads, broadcast via LDS).
    if (t < RPB) {
        const float H0 = (sh0[t][0] + sh0[t][1] + sh0[t][2] + sh0[t][3]) * a_scale[0];
        const float H1 = (sh1[t][0] + sh1[t][1] + sh1[t][2] + sh1[t][3]) * a_scale[1];
        sh0[t][0] = H0;
        sh1[t][0] = H1;
    }
    __syncthreads();

    // ---- Phase 2: streaming non-temporal write of out.
#pragma unroll
    for (int r = 0; r < RPB; ++r) {
        const float H0 = sh0[r][0];   // wave-uniform broadcast
        const float H1 = sh1[r][0];
#pragma unroll
        for (int k = 0; k < 4; ++k) {
            f32x4 o;
            o.x = H0 * bb0[4*k+0] + H1 * bb1[4*k+0];
            o.y = H0 * bb0[4*k+1] + H1 * bb1[4*k+1];
            o.z = H0 * bb0[4*k+2] + H1 * bb1[4*k+2];
            o.w = H0 * bb0[4*k+3] + H1 * bb1[4*k+3];
            __builtin_nontemporal_store(o, &o4[r * (QL_D / 4) + t + 256 * k]);
        }
    }
}

extern "C" void kernel_launch(void* const* d_in, const int* in_sizes, int n_in,
                              void* d_out, int out_size, void* d_ws, size_t ws_size,
                              hipStream_t stream) {
    const float* x       = (const float*)d_in[0];   // [4,4096,4096]
    const int*   a_q     = (const int*)d_in[1];     // [2,4096]
    const float* a_scale = (const float*)d_in[2];   // [2]
    const int*   b_q     = (const int*)d_in[3];     // [4096,2]
    const float* b_scale = (const float*)d_in[4];   // [4096]
    float*       out     = (float*)d_out;           // [4,4096,4096]

    qlora_fused_kernel<<<QL_ROWS / RPB, 256, 0, stream>>>(
        x, a_q, a_scale, b_q, b_scale, out);
}

// Round 2
// 430.158 us; speedup vs baseline: 1.0489x; 1.0034x over previous
//
#include <hip/hip_runtime.h>

// QLoRA rank-2, fused, WAVE-AUTONOMOUS formulation.
//   out[row,d] = 0.5*b_scale[d]*(H0*b_q[d,0] + H1*b_q[d,1]),
//   H_r = a_scale[r] * sum_d x[row,d]*a_q[r,d]
// One wave owns one full row: read 4096 floats (16 float4/lane), reduce the
// rank-2 dot IN-WAVE (shuffles only — no LDS round-trip, no __syncthreads on
// the row path), broadcast H, write the row. Waves stream independently, so
// reads of row r+1 overlap writes of row r across the 16 resident waves/CU.
// Dequantized A and pre-scaled B live in LDS (64 KB), staged once per block.

#define QL_D    4096
#define QL_ROWS 16384
#define THREADS 512            // 8 waves
#define ROWS_PER_WAVE 2
#define ROWS_PER_BLOCK (8 * ROWS_PER_WAVE)   // 16

typedef float f32x4 __attribute__((ext_vector_type(4)));

__global__ __launch_bounds__(THREADS, 4) void qlora_wave_kernel(
    const float* __restrict__ x,        // [ROWS, D]
    const int*   __restrict__ a_q,      // [2, D]   (int8 values widened to i32)
    const float* __restrict__ a_scale,  // [2]
    const int*   __restrict__ b_q,      // [D, 2]
    const float* __restrict__ b_scale,  // [D]
    float*       __restrict__ out)      // [ROWS, D]
{
    const int t    = threadIdx.x;
    const int wave = t >> 6;
    const int lane = t & 63;

    // ---- LDS: fa0|fa1 (dequant A, a_scale deferred) and bb0|bb1 (0.5*bs*B).
    __shared__ float lds[4 * QL_D];     // 64 KB
    float* fa0 = lds;
    float* fa1 = lds + QL_D;
    float* bb0 = lds + 2 * QL_D;
    float* bb1 = lds + 3 * QL_D;

    {
        const int4*   aq4 = (const int4*)a_q;      // 1024 int4 per rank row
        const int4*   bq4 = (const int4*)b_q;      // 2 d-entries per int4
        const float4* bs4 = (const float4*)b_scale;
#pragma unroll
        for (int k = 0; k < 2; ++k) {
            const int idx = t + THREADS * k;       // float4 index, 0..1023
            const int4 qa0 = aq4[idx];
            const int4 qa1 = aq4[QL_D / 4 + idx];
            ((f32x4*)fa0)[idx] =
                (f32x4){(float)qa0.x, (float)qa0.y, (float)qa0.z, (float)qa0.w};
            ((f32x4*)fa1)[idx] =
                (f32x4){(float)qa1.x, (float)qa1.y, (float)qa1.z, (float)qa1.w};

            const int4   qb0 = bq4[2 * idx];
            const int4   qb1 = bq4[2 * idx + 1];
            const float4 bs  = bs4[idx];
            ((f32x4*)bb0)[idx] = (f32x4){0.5f * bs.x * (float)qb0.x,
                                         0.5f * bs.y * (float)qb0.z,
                                         0.5f * bs.z * (float)qb1.x,
                                         0.5f * bs.w * (float)qb1.z};
            ((f32x4*)bb1)[idx] = (f32x4){0.5f * bs.x * (float)qb0.y,
                                         0.5f * bs.y * (float)qb0.w,
                                         0.5f * bs.z * (float)qb1.y,
                                         0.5f * bs.w * (float)qb1.w};
        }
    }
    const float as0 = a_scale[0];
    const float as1 = a_scale[1];
    __syncthreads();   // the ONLY barrier — weights ready; rows are wave-local now

    const f32x4* fa0v = (const f32x4*)fa0;
    const f32x4* fa1v = (const f32x4*)fa1;
    const f32x4* bb0v = (const f32x4*)bb0;
    const f32x4* bb1v = (const f32x4*)bb1;

    const int rowbase = blockIdx.x * ROWS_PER_BLOCK + wave * ROWS_PER_WAVE;

    for (int rr = 0; rr < ROWS_PER_WAVE; ++rr) {
        const int row = rowbase + rr;
        const f32x4* xr = (const f32x4*)(x   + (size_t)row * QL_D);
        f32x4*       orw = (f32x4*)      (out + (size_t)row * QL_D);

        // ---- Phase 1: rank-2 dot over the row (split accumulators for ILP).
        float h0a = 0.f, h0b = 0.f, h1a = 0.f, h1b = 0.f;
#pragma unroll 8
        for (int k = 0; k < 16; ++k) {
            const int d4 = lane + 64 * k;
            const f32x4 xv = __builtin_nontemporal_load(&xr[d4]);
            const f32x4 a0 = fa0v[d4];   // conflict-free: 16 B stride per lane
            const f32x4 a1 = fa1v[d4];
            h0a += xv.x * a0.x + xv.y * a0.y;
            h0b += xv.z * a0.z + xv.w * a0.w;
            h1a += xv.x * a1.x + xv.y * a1.y;
            h1b += xv.z * a1.z + xv.w * a1.w;
        }
        float h0 = h0a + h0b;
        float h1 = h1a + h1b;
#pragma unroll
        for (int off = 32; off > 0; off >>= 1) {
            h0 += __shfl_down(h0, off, 64);
            h1 += __shfl_down(h1, off, 64);
        }
        const float H0 = __shfl(h0, 0, 64) * as0;   // broadcast, apply a_scale
        const float H1 = __shfl(h1, 0, 64) * as1;

        // ---- Phase 2: stream the output row.
#pragma unroll 8
        for (int k = 0; k < 16; ++k) {
            const int d4 = lane + 64 * k;
            const f32x4 b0 = bb0v[d4];
            const f32x4 b1 = bb1v[d4];
            f32x4 o;
            o.x = H0 * b0.x + H1 * b1.x;
            o.y = H0 * b0.y + H1 * b1.y;
            o.z = H0 * b0.z + H1 * b1.z;
            o.w = H0 * b0.w + H1 * b1.w;
            __builtin_nontemporal_store(o, &orw[d4]);
        }
    }
}

extern "C" void kernel_launch(void* const* d_in, const int* in_sizes, int n_in,
                              void* d_out, int out_size, void* d_ws, size_t ws_size,
                              hipStream_t stream) {
    const float* x       = (const float*)d_in[0];   // [4,4096,4096]
    const int*   a_q     = (const int*)d_in[1];     // [2,4096]
    const float* a_scale = (const float*)d_in[2];   // [2]
    const int*   b_q     = (const int*)d_in[3];     // [4096,2]
    const float* b_scale = (const float*)d_in[4];   // [4096]
    float*       out     = (float*)d_out;           // [4,4096,4096]

    qlora_wave_kernel<<<QL_ROWS / ROWS_PER_BLOCK, THREADS, 0, stream>>>(
        x, a_q, a_scale, b_q, b_scale, out);
}